// Round 1
// baseline (280.273 us; speedup 1.0000x reference)
//
#include <hip/hip_runtime.h>
#include <math.h>

#define BATCH 16
#define NCLS 80
#define TOPK 100
#define NBOX 22743
#define NSLOT (NCLS*TOPK)   // 8000 per image

#define P0 361
#define P1 1444
#define P2 5776
#define G0 19
#define G1 38
#define G2 76
#define OFF1 1083
#define OFF2 5415

__device__ __forceinline__ float sigf(float x){ return 1.0f/(1.0f + expf(-x)); }

// ---------------- decode: boxes + sigmoid(conf) ----------------
__global__ __launch_bounds__(256)
void decode_kernel(const float* __restrict__ f0, const float* __restrict__ f1,
                   const float* __restrict__ f2, const float* __restrict__ anchors,
                   const float* __restrict__ ishape,
                   float* __restrict__ boxes, float* __restrict__ sconf)
{
    int r = blockIdx.x*blockDim.x + threadIdx.x;
    int b = blockIdx.y;
    if (r >= NBOX) return;
    const float* f; int a, p, P, G, off, abase;
    if (r < 3*P0)      { int q = r;        a=q/P0; p=q-a*P0; P=P0; G=G0; off=0;    f=f0; abase=6; }
    else if (r < OFF2) { int q = r-3*P0;   a=q/P1; p=q-a*P1; P=P1; G=G1; off=OFF1; f=f1; abase=3; }
    else               { int q = r-OFF2;   a=q/P2; p=q-a*P2; P=P2; G=G2; off=OFF2; f=f2; abase=0; }
    const float* fb = f + ((size_t)b*255 + a*85)*(size_t)P;
    float tx = fb[(size_t)0*P + p];
    float ty = fb[(size_t)1*P + p];
    float tw = fb[(size_t)2*P + p];
    float th = fb[(size_t)3*P + p];
    float tc = fb[(size_t)4*P + p];
    int yy = p / G, xx = p - yy*G;
    float g = (float)G;
    float aw = anchors[(abase+a)*2+0];
    float ah = anchors[(abase+a)*2+1];
    // box_xy = (sigmoid + grid)/[gh,gw]; box_wh = anchors*exp/input_hw
    float xn = (sigf(tx) + (float)xx) / g;
    float yn = (sigf(ty) + (float)yy) / g;
    float wn = aw * expf(tw) / 608.0f;
    float hn = ah * expf(th) / 608.0f;
    // letterbox correction
    float ih = ishape[0], iw = ishape[1];
    float m  = fminf(608.0f/ih, 608.0f/iw);
    float nh = rintf(ih*m), nw = rintf(iw*m);      // jnp.round = half-to-even = rintf
    float offy = (608.0f - nh) / 2.0f / 608.0f;
    float offx = (608.0f - nw) / 2.0f / 608.0f;
    float scy = 608.0f/nh, scx = 608.0f/nw;
    float y = (yn - offy)*scy;
    float x = (xn - offx)*scx;
    float hh = hn*scy, ww = wn*scx;
    int n = off + p*3 + a;                          // reference flatten order: (y,x) pixel, then anchor
    size_t o = ((size_t)b*NBOX + n)*4;
    boxes[o+0] = (y - hh/2.0f)*ih;
    boxes[o+1] = (x - ww/2.0f)*iw;
    boxes[o+2] = (y + hh/2.0f)*ih;
    boxes[o+3] = (x + ww/2.0f)*iw;
    sconf[(size_t)b*NBOX + n] = sigf(tc);
}

// ---------------- per-(b,c) exact top-100 ----------------
__device__ __forceinline__ void scan_scales(const float* __restrict__ f0, const float* __restrict__ f1,
        const float* __restrict__ f2, const float* __restrict__ sconf,
        int b, int c, int tid, int pass, int Tb,
        int* hist, float* cs, int* ci, int* cnt)
{
    const float* fs[3]  = {f0, f1, f2};
    const int   Ps[3]   = {P0, P1, P2};
    const int   offs[3] = {0, OFF1, OFF2};
    for (int s=0; s<3; s++){
        const float* f = fs[s]; const int P = Ps[s]; const int off = offs[s];
        for (int a=0; a<3; a++){
            const float* base = f + ((size_t)b*255 + a*85 + 5 + c)*(size_t)P;
            const float* cf   = sconf + (size_t)b*NBOX + off + a;
            for (int p=tid; p<P; p+=256){
                float sc = cf[(size_t)p*3] * sigf(base[p]);
                if (sc > 0.3f){
                    // float bits are monotonic for positive floats; scores in (0.3, 1.0]
                    int bin = (int)(__float_as_uint(sc)>>16) - 0x3E99;
                    bin = bin < 0 ? 0 : (bin > 255 ? 255 : bin);
                    if (pass == 0) atomicAdd(&hist[bin], 1);
                    else if (bin >= Tb){
                        int pos = atomicAdd(cnt, 1);
                        if (pos < 1024){ cs[pos] = sc; ci[pos] = off + p*3 + a; }
                    }
                }
            }
        }
    }
}

__global__ __launch_bounds__(256)
void select_kernel(const float* __restrict__ f0, const float* __restrict__ f1,
                   const float* __restrict__ f2, const float* __restrict__ sconf,
                   int* __restrict__ tk_idx, float* __restrict__ tk_scr)
{
    int c = blockIdx.x, b = blockIdx.y, tid = threadIdx.x;
    __shared__ int   hist[256];
    __shared__ int   sufA[256], sufB[256];
    __shared__ float cs[1024];
    __shared__ int   ci[1024];
    __shared__ int   cnt, Tb;
    hist[tid] = 0;
    for (int t=tid; t<1024; t+=256){ cs[t] = -INFINITY; ci[t] = 0x7FFFFFFF; }
    if (tid == 0){ cnt = 0; Tb = 0; }
    __syncthreads();

    // pass 0: histogram of scores > 0.3
    scan_scales(f0,f1,f2,sconf,b,c,tid,0,0,hist,cs,ci,&cnt);
    __syncthreads();

    // inclusive suffix sum over 256 bins (Hillis-Steele, ping-pong)
    sufA[tid] = hist[tid];
    __syncthreads();
    int* cur = sufA; int* nxt = sufB;
    for (int d=1; d<256; d<<=1){
        int v = cur[tid] + ((tid+d) < 256 ? cur[tid+d] : 0);
        nxt[tid] = v;
        __syncthreads();
        int* t_ = cur; cur = nxt; nxt = t_;
    }
    // threshold bin: largest T with suffix(T) >= 100 (else 0 -> take all)
    if (cur[tid] >= TOPK && (tid == 255 || cur[tid+1] < TOPK)) Tb = tid;
    __syncthreads();
    int TbL = Tb;

    // pass 1: compact candidates (bin >= Tb)
    scan_scales(f0,f1,f2,sconf,b,c,tid,1,TbL,hist,cs,ci,&cnt);
    __syncthreads();

    // bitonic sort 1024: score desc, idx asc (exact jax top_k order)
    for (int k=2; k<=1024; k<<=1){
        for (int j=k>>1; j>0; j>>=1){
            for (int t=tid; t<1024; t+=256){
                int ixj = t ^ j;
                if (ixj > t){
                    float s1 = cs[t], s2 = cs[ixj];
                    int   i1 = ci[t], i2 = ci[ixj];
                    bool b2_first = (s2 > s1) || (s2 == s1 && i2 < i1); // elem2 should come first
                    bool b1_first = (s1 > s2) || (s1 == s2 && i1 < i2);
                    bool desc = ((t & k) == 0);
                    bool sw = desc ? b2_first : b1_first;
                    if (sw){ cs[t]=s2; cs[ixj]=s1; ci[t]=i2; ci[ixj]=i1; }
                }
            }
            __syncthreads();
        }
    }

    if (tid < TOPK){
        float s = cs[tid];
        bool ok = (s > 0.3f);           // sentinels are -inf; all compacted are > 0.3
        int o = (b*NCLS + c)*TOPK + tid;
        tk_scr[o] = ok ? s : -1.0f;
        tk_idx[o] = ok ? ci[tid] : -1;
    }
}

// ---------------- per-(b,c) sequential NMS ----------------
__global__ __launch_bounds__(128)
void nms_kernel(const float* __restrict__ boxes, const int* __restrict__ tk_idx,
                const float* __restrict__ tk_scr, float* __restrict__ out)
{
    int c = blockIdx.x, b = blockIdx.y, tid = threadIdx.x;
    __shared__ float by1[TOPK], bx1[TOPK], by2[TOPK], bx2[TOPK], bar[TOPK], bsc[TOPK];
    __shared__ int keep[TOPK];
    if (tid < TOPK){
        int o = (b*NCLS + c)*TOPK + tid;
        int idx = tk_idx[o];
        float sc = tk_scr[o];
        float y1=0.f, x1=0.f, y2=0.f, x2=0.f;
        if (idx >= 0){
            size_t q = ((size_t)b*NBOX + idx)*4;
            y1 = boxes[q+0]; x1 = boxes[q+1]; y2 = boxes[q+2]; x2 = boxes[q+3];
        }
        by1[tid]=y1; bx1[tid]=x1; by2[tid]=y2; bx2[tid]=x2;
        bar[tid] = (y2-y1)*(x2-x1);
        bsc[tid] = sc;
        keep[tid] = (idx >= 0) ? 1 : 0;   // keep starts as valid; keep ⊆ valid thereafter
    }
    __syncthreads();
    for (int i=0; i<TOPK; i++){
        int act = keep[i];
        if (act && tid < TOPK && tid > i && keep[tid]){
            float iy1 = fmaxf(by1[i], by1[tid]);
            float ix1 = fmaxf(bx1[i], bx1[tid]);
            float iy2 = fminf(by2[i], by2[tid]);
            float ix2 = fminf(bx2[i], bx2[tid]);
            float inter = fmaxf(iy2-iy1, 0.0f)*fmaxf(ix2-ix1, 0.0f);
            float iou = inter / (bar[i] + bar[tid] - inter + 1e-9f);
            if (iou > 0.3f) keep[tid] = 0;
        }
        __syncthreads();
    }
    if (tid < TOPK){
        size_t o5 = ((size_t)((b*NCLS + c)*TOPK + tid))*5;
        float k = keep[tid] ? 1.0f : 0.0f;
        out[o5+0] = by1[tid]*k;
        out[o5+1] = bx1[tid]*k;
        out[o5+2] = by2[tid]*k;
        out[o5+3] = bx2[tid]*k;
        out[o5+4] = bsc[tid]*k;
    }
}

// ---------------- per-image top-50 cap ----------------
__global__ __launch_bounds__(256)
void cap_kernel(float* __restrict__ out)
{
    int b = blockIdx.x, tid = threadIdx.x;
    __shared__ float sv[NSLOT];
    __shared__ unsigned char msk[NSLOT];
    __shared__ float rv[256];
    __shared__ int   ri[256];
    for (int u=tid; u<NSLOT; u+=256){
        sv[u] = out[((size_t)b*NSLOT + u)*5 + 4];
        msk[u] = 0;
    }
    __syncthreads();
    for (int it=0; it<50; it++){
        float bestv = -INFINITY; int besti = 0x7FFFFFFF;
        for (int u=tid; u<NSLOT; u+=256){
            float v = sv[u];
            if (v > bestv){ bestv = v; besti = u; }   // strict > : lowest index wins ties
        }
        rv[tid] = bestv; ri[tid] = besti;
        __syncthreads();
        for (int o=128; o>0; o>>=1){
            if (tid < o){
                float v2 = rv[tid+o]; int i2 = ri[tid+o];
                if (v2 > rv[tid] || (v2 == rv[tid] && i2 < ri[tid])){ rv[tid] = v2; ri[tid] = i2; }
            }
            __syncthreads();
        }
        if (tid == 0){ msk[ri[0]] = 1; sv[ri[0]] = -INFINITY; }
        __syncthreads();
    }
    for (int u=tid; u<NSLOT; u+=256){
        if (!msk[u]){
            size_t o5 = ((size_t)b*NSLOT + u)*5;
            out[o5+0]=0.f; out[o5+1]=0.f; out[o5+2]=0.f; out[o5+3]=0.f; out[o5+4]=0.f;
        }
    }
}

extern "C" void kernel_launch(void* const* d_in, const int* in_sizes, int n_in,
                              void* d_out, int out_size, void* d_ws, size_t ws_size,
                              hipStream_t stream)
{
    const float* f0 = (const float*)d_in[0];
    const float* f1 = (const float*)d_in[1];
    const float* f2 = (const float*)d_in[2];
    const float* anchors = (const float*)d_in[3];
    const float* ishape  = (const float*)d_in[4];
    float* out = (float*)d_out;

    float* boxes = (float*)d_ws;                                  // B*NBOX*4 floats
    float* sconf = boxes + (size_t)BATCH*NBOX*4;                  // B*NBOX floats
    int*   tk_idx = (int*)(sconf + (size_t)BATCH*NBOX);           // B*80*100 ints
    float* tk_scr = (float*)(tk_idx + BATCH*NCLS*TOPK);           // B*80*100 floats

    dim3 dgrid((NBOX + 255)/256, BATCH);
    decode_kernel<<<dgrid, 256, 0, stream>>>(f0, f1, f2, anchors, ishape, boxes, sconf);

    dim3 sgrid(NCLS, BATCH);
    select_kernel<<<sgrid, 256, 0, stream>>>(f0, f1, f2, sconf, tk_idx, tk_scr);

    nms_kernel<<<sgrid, 128, 0, stream>>>(boxes, tk_idx, tk_scr, out);

    cap_kernel<<<BATCH, 256, 0, stream>>>(out);
}

// Round 2
// 245.656 us; speedup vs baseline: 1.1409x; 1.1409x over previous
//
#include <hip/hip_runtime.h>
#include <math.h>

#define BATCH 16
#define NCLS 80
#define TOPK 100
#define NBOX 22743
#define NSLOT (NCLS*TOPK)   // 8000 per image
#define TPAD 22752          // padded (s,a)-major total per image

#define P0 361
#define P1 1444
#define P2 5776

__device__ __forceinline__ float sigf(float x){ return 1.0f/(1.0f + expf(-x)); }

// ---------------- decode: boxes + conf + rejection-logit (padded (s,a)-major) ----
__global__ __launch_bounds__(256)
void decode_kernel(const float* __restrict__ f0, const float* __restrict__ f1,
                   const float* __restrict__ f2, const float* __restrict__ anchors,
                   const float* __restrict__ ishape,
                   float* __restrict__ boxes, float* __restrict__ conf2,
                   float* __restrict__ tlog2)
{
    int r = blockIdx.x*blockDim.x + threadIdx.x;
    int b = blockIdx.y;
    if (r >= TPAD) return;
    int sa, p;
    if (r < 1092){ sa = r/364; p = r - sa*364; }
    else if (r < 5424){ int q = r-1092; sa = 3 + q/1444; p = q - (sa-3)*1444; }
    else { int q = r-5424; sa = 6 + q/5776; p = q - (sa-6)*5776; }
    int s = (sa>=6)?2:((sa>=3)?1:0);
    int a = sa - 3*s;
    const float* f; int P, G, off, abase;
    if (s==0){ f=f0; P=P0; G=19; off=0;    abase=6; }
    else if (s==1){ f=f1; P=P1; G=38; off=1083; abase=3; }
    else        { f=f2; P=P2; G=76; off=5415; abase=0; }
    size_t cidx = (size_t)b*TPAD + r;
    if (p >= P){ conf2[cidx] = 0.0f; tlog2[cidx] = INFINITY; return; }

    const float* fb = f + ((size_t)b*255 + a*85)*(size_t)P;
    float tx = fb[(size_t)0*P + p];
    float ty = fb[(size_t)1*P + p];
    float tw = fb[(size_t)2*P + p];
    float th = fb[(size_t)3*P + p];
    float tc = fb[(size_t)4*P + p];
    int yy = p / G, xx = p - yy*G;
    float g = (float)G;
    float aw = anchors[(abase+a)*2+0];
    float ah = anchors[(abase+a)*2+1];
    float xn = (sigf(tx) + (float)xx) / g;
    float yn = (sigf(ty) + (float)yy) / g;
    float wn = aw * expf(tw) / 608.0f;
    float hn = ah * expf(th) / 608.0f;
    float ih = ishape[0], iw = ishape[1];
    float m  = fminf(608.0f/ih, 608.0f/iw);
    float nh = rintf(ih*m), nw = rintf(iw*m);
    float offy = (608.0f - nh) / 2.0f / 608.0f;
    float offx = (608.0f - nw) / 2.0f / 608.0f;
    float scy = 608.0f/nh, scx = 608.0f/nw;
    float y = (yn - offy)*scy;
    float x = (xn - offx)*scx;
    float hh = hn*scy, ww = wn*scx;
    int n = off + p*3 + a;
    size_t o = ((size_t)b*NBOX + n)*4;
    boxes[o+0] = (y - hh/2.0f)*ih;
    boxes[o+1] = (x - ww/2.0f)*iw;
    boxes[o+2] = (y + hh/2.0f)*ih;
    boxes[o+3] = (x + ww/2.0f)*iw;

    float cf = sigf(tc);
    conf2[cidx] = cf;
    float t;
    if (cf > 0.2951f){ float xr = 0.295f/cf; t = logf(xr/(1.0f - xr)); }
    else t = INFINITY;
    tlog2[cidx] = t;
}

// ---------------- per-(b,c) scan with early rejection ----------------
__device__ __forceinline__ void scan2(const float* __restrict__ f0, const float* __restrict__ f1,
        const float* __restrict__ f2, const float* __restrict__ conf2,
        const float* __restrict__ tlog2,
        int b, int c, int tid, int pass, int Tb,
        int* hist, float* cs, int* ci, int* cnt)
{
    const float* fs[3] = {f0, f1, f2};
    const int Pact[9] = {361,361,361,1444,1444,1444,5776,5776,5776};
    const int Ppad[9] = {364,364,364,1444,1444,1444,5776,5776,5776};
    const int gsa[9]  = {0,364,728,1092,2536,3980,5424,11200,16976};
    const int offs_s[3] = {0,1083,5415};
#pragma unroll
    for (int sa=0; sa<9; sa++){
        const int s = sa/3, a = sa - 3*(sa/3);
        const int P = Pact[sa];
        const float* prob = fs[s] + ((size_t)b*255 + a*85 + 5 + c)*(size_t)P;
        const float* tl = tlog2 + (size_t)b*TPAD + gsa[sa];
        const float* cf = conf2 + (size_t)b*TPAD + gsa[sa];
        const int nb = offs_s[s] + a;
        const int q4 = Ppad[sa] >> 2;
        for (int i=tid; i<q4; i+=256){
            int p = i<<2;
            float4 t4 = *(const float4*)(tl + p);
            float pr0,pr1,pr2,pr3;
            if (p + 3 < P){
                pr0 = prob[p]; pr1 = prob[p+1]; pr2 = prob[p+2]; pr3 = prob[p+3];
            } else {
                pr0 = (p   < P) ? prob[p]   : -INFINITY;
                pr1 = (p+1 < P) ? prob[p+1] : -INFINITY;
                pr2 = (p+2 < P) ? prob[p+2] : -INFINITY;
                pr3 = (p+3 < P) ? prob[p+3] : -INFINITY;
            }
            bool h0 = pr0 > t4.x, h1 = pr1 > t4.y, h2 = pr2 > t4.z, h3 = pr3 > t4.w;
            if (h0|h1|h2|h3){
                float4 c4 = *(const float4*)(cf + p);
#define DOJ(J, PR, CC, HH) \
                if (HH){ float sc = (CC) * sigf(PR); \
                    if (sc > 0.3f){ \
                        int bin = (int)(__float_as_uint(sc)>>16) - 0x3E99; \
                        bin = bin < 0 ? 0 : (bin > 255 ? 255 : bin); \
                        if (pass == 0) atomicAdd(&hist[bin], 1); \
                        else if (bin >= Tb){ \
                            int pos = atomicAdd(cnt, 1); \
                            if (pos < 1024){ cs[pos] = sc; ci[pos] = nb + 3*(p+J); } } } }
                DOJ(0,pr0,c4.x,h0)
                DOJ(1,pr1,c4.y,h1)
                DOJ(2,pr2,c4.z,h2)
                DOJ(3,pr3,c4.w,h3)
#undef DOJ
            }
        }
    }
}

__global__ __launch_bounds__(256)
void select_kernel(const float* __restrict__ f0, const float* __restrict__ f1,
                   const float* __restrict__ f2, const float* __restrict__ conf2,
                   const float* __restrict__ tlog2,
                   int* __restrict__ tk_idx, float* __restrict__ tk_scr)
{
    int c = blockIdx.x, b = blockIdx.y, tid = threadIdx.x;
    __shared__ int   hist[256];
    __shared__ int   sufA[256], sufB[256];
    __shared__ float cs[1024];
    __shared__ int   ci[1024];
    __shared__ int   cnt, Tb;
    hist[tid] = 0;
    for (int t=tid; t<1024; t+=256){ cs[t] = -INFINITY; ci[t] = 0x7FFFFFFF; }
    if (tid == 0){ cnt = 0; Tb = 0; }
    __syncthreads();

    // pass 0: histogram of scores > 0.3
    scan2(f0,f1,f2,conf2,tlog2,b,c,tid,0,0,hist,cs,ci,&cnt);
    __syncthreads();

    // inclusive suffix sum over 256 bins
    sufA[tid] = hist[tid];
    __syncthreads();
    int* cur = sufA; int* nxt = sufB;
    for (int d=1; d<256; d<<=1){
        int v = cur[tid] + ((tid+d) < 256 ? cur[tid+d] : 0);
        nxt[tid] = v;
        __syncthreads();
        int* t_ = cur; cur = nxt; nxt = t_;
    }
    if (cur[tid] >= TOPK && (tid == 255 || cur[tid+1] < TOPK)) Tb = tid;
    __syncthreads();
    int TbL = Tb;

    // pass 1: compact candidates (bin >= Tb)
    scan2(f0,f1,f2,conf2,tlog2,b,c,tid,1,TbL,hist,cs,ci,&cnt);
    __syncthreads();

    // bitonic sort 1024: score desc, idx asc
    for (int k=2; k<=1024; k<<=1){
        for (int j=k>>1; j>0; j>>=1){
            for (int t=tid; t<1024; t+=256){
                int ixj = t ^ j;
                if (ixj > t){
                    float s1 = cs[t], s2 = cs[ixj];
                    int   i1 = ci[t], i2 = ci[ixj];
                    bool b2_first = (s2 > s1) || (s2 == s1 && i2 < i1);
                    bool b1_first = (s1 > s2) || (s1 == s2 && i1 < i2);
                    bool desc = ((t & k) == 0);
                    bool sw = desc ? b2_first : b1_first;
                    if (sw){ cs[t]=s2; cs[ixj]=s1; ci[t]=i2; ci[ixj]=i1; }
                }
            }
            __syncthreads();
        }
    }

    if (tid < TOPK){
        float s = cs[tid];
        bool ok = (s > 0.3f);
        int o = (b*NCLS + c)*TOPK + tid;
        tk_scr[o] = ok ? s : -1.0f;
        tk_idx[o] = ok ? ci[tid] : -1;
    }
}

// ---------------- per-(b,c) sequential NMS: single wave, no barriers ----------
__global__ __launch_bounds__(64)
void nms_kernel(const float* __restrict__ boxes, const int* __restrict__ tk_idx,
                const float* __restrict__ tk_scr, float* __restrict__ out)
{
    int c = blockIdx.x, b = blockIdx.y, lane = threadIdx.x;
    int o0 = (b*NCLS + c)*TOPK;
    float ay1=0.f,ax1=0.f,ay2=0.f,ax2=0.f,aar=0.f,asc=0.f; int ak=0;
    float by1=0.f,bx1=0.f,by2=0.f,bx2=0.f,bar_=0.f,bsc=0.f; int bk=0;
    {
        int idx = tk_idx[o0+lane]; asc = tk_scr[o0+lane];
        if (idx >= 0){
            size_t q = ((size_t)b*NBOX + idx)*4;
            ay1=boxes[q]; ax1=boxes[q+1]; ay2=boxes[q+2]; ax2=boxes[q+3]; ak=1;
        }
        aar = (ay2-ay1)*(ax2-ax1);
    }
    if (lane + 64 < TOPK){
        int idx = tk_idx[o0+lane+64]; bsc = tk_scr[o0+lane+64];
        if (idx >= 0){
            size_t q = ((size_t)b*NBOX + idx)*4;
            by1=boxes[q]; bx1=boxes[q+1]; by2=boxes[q+2]; bx2=boxes[q+3]; bk=1;
        }
        bar_ = (by2-by1)*(bx2-bx1);
    }
    for (int i=0; i<TOPK; i++){
        float iy1,ix1,iy2,ix2,iar; int ik;
        if (i < 64){
            iy1=__shfl(ay1,i); ix1=__shfl(ax1,i); iy2=__shfl(ay2,i); ix2=__shfl(ax2,i);
            iar=__shfl(aar,i); ik=__shfl(ak,i);
        } else {
            int l = i - 64;
            iy1=__shfl(by1,l); ix1=__shfl(bx1,l); iy2=__shfl(by2,l); ix2=__shfl(bx2,l);
            iar=__shfl(bar_,l); ik=__shfl(bk,l);
        }
        if (ik){
            if (ak && lane > i){
                float t1=fmaxf(iy1,ay1), t2=fmaxf(ix1,ax1);
                float t3=fminf(iy2,ay2), t4=fminf(ix2,ax2);
                float inter = fmaxf(t3-t1,0.0f)*fmaxf(t4-t2,0.0f);
                float iou = inter/(iar + aar - inter + 1e-9f);
                if (iou > 0.3f) ak = 0;
            }
            if (bk && lane + 64 > i){
                float t1=fmaxf(iy1,by1), t2=fmaxf(ix1,bx1);
                float t3=fminf(iy2,by2), t4=fminf(ix2,bx2);
                float inter = fmaxf(t3-t1,0.0f)*fmaxf(t4-t2,0.0f);
                float iou = inter/(iar + bar_ - inter + 1e-9f);
                if (iou > 0.3f) bk = 0;
            }
        }
    }
    {
        float k = ak ? 1.0f : 0.0f;
        size_t o5 = ((size_t)(o0+lane))*5;
        out[o5+0]=ay1*k; out[o5+1]=ax1*k; out[o5+2]=ay2*k; out[o5+3]=ax2*k; out[o5+4]=asc*k;
    }
    if (lane + 64 < TOPK){
        float k = bk ? 1.0f : 0.0f;
        size_t o5 = ((size_t)(o0+lane+64))*5;
        out[o5+0]=by1*k; out[o5+1]=bx1*k; out[o5+2]=by2*k; out[o5+3]=bx2*k; out[o5+4]=bsc*k;
    }
}

// ---------------- per-image top-50 cap (1024 threads, shfl reductions) --------
__global__ __launch_bounds__(1024)
void cap_kernel(float* __restrict__ out)
{
    int b = blockIdx.x, tid = threadIdx.x;
    int lane = tid & 63, w = tid >> 6;
    __shared__ float sv[NSLOT];
    __shared__ unsigned char msk[NSLOT];
    __shared__ float wrv[16];
    __shared__ int   wri[16];
    for (int u=tid; u<NSLOT; u+=1024){
        sv[u] = out[((size_t)b*NSLOT + u)*5 + 4];
        msk[u] = 0;
    }
    __syncthreads();
    for (int it=0; it<50; it++){
        float bv = -INFINITY; int bi = 0x7FFFFFFF;
        for (int u=tid; u<NSLOT; u+=1024){
            float v = sv[u];
            if (v > bv){ bv = v; bi = u; }
        }
        for (int off=32; off; off>>=1){
            float v2 = __shfl_xor(bv, off); int i2 = __shfl_xor(bi, off);
            if (v2 > bv || (v2 == bv && i2 < bi)){ bv = v2; bi = i2; }
        }
        if (lane == 0){ wrv[w] = bv; wri[w] = bi; }
        __syncthreads();
        if (w == 0){
            float v = (lane < 16) ? wrv[lane] : -INFINITY;
            int   i = (lane < 16) ? wri[lane] : 0x7FFFFFFF;
            for (int off=8; off; off>>=1){
                float v2 = __shfl_xor(v, off); int i2 = __shfl_xor(i, off);
                if (v2 > v || (v2 == v && i2 < i)){ v = v2; i = i2; }
            }
            if (lane == 0){ msk[i] = 1; sv[i] = -INFINITY; }
        }
        __syncthreads();
    }
    for (int u=tid; u<NSLOT; u+=1024){
        if (!msk[u]){
            size_t o5 = ((size_t)b*NSLOT + u)*5;
            out[o5+0]=0.f; out[o5+1]=0.f; out[o5+2]=0.f; out[o5+3]=0.f; out[o5+4]=0.f;
        }
    }
}

extern "C" void kernel_launch(void* const* d_in, const int* in_sizes, int n_in,
                              void* d_out, int out_size, void* d_ws, size_t ws_size,
                              hipStream_t stream)
{
    const float* f0 = (const float*)d_in[0];
    const float* f1 = (const float*)d_in[1];
    const float* f2 = (const float*)d_in[2];
    const float* anchors = (const float*)d_in[3];
    const float* ishape  = (const float*)d_in[4];
    float* out = (float*)d_out;

    float* boxes = (float*)d_ws;                               // 16*22743*4 floats
    float* conf2 = boxes + (size_t)BATCH*NBOX*4;               // 16*22752
    float* tlog2 = conf2 + (size_t)BATCH*TPAD;                 // 16*22752
    int*   tk_idx = (int*)(tlog2 + (size_t)BATCH*TPAD);        // 16*80*100
    float* tk_scr = (float*)(tk_idx + BATCH*NCLS*TOPK);        // 16*80*100

    dim3 dgrid((TPAD + 255)/256, BATCH);
    decode_kernel<<<dgrid, 256, 0, stream>>>(f0, f1, f2, anchors, ishape,
                                             boxes, conf2, tlog2);

    dim3 sgrid(NCLS, BATCH);
    select_kernel<<<sgrid, 256, 0, stream>>>(f0, f1, f2, conf2, tlog2, tk_idx, tk_scr);

    nms_kernel<<<sgrid, 64, 0, stream>>>(boxes, tk_idx, tk_scr, out);

    cap_kernel<<<BATCH, 1024, 0, stream>>>(out);
}

// Round 3
// 217.699 us; speedup vs baseline: 1.2874x; 1.1284x over previous
//
#include <hip/hip_runtime.h>
#include <math.h>

#define BATCH 16
#define NCLS 80
#define TOPK 100
#define NBOX 22743
#define NSLOT (NCLS*TOPK)   // 8000 per image
#define TPAD 22752          // padded (s,a)-major total per image
#define CAP 1024

#define P0 361
#define P1 1444
#define P2 5776

__device__ __forceinline__ float sigf(float x){ return 1.0f/(1.0f + expf(-x)); }

// ---------------- decode: boxes + conf (padded (s,a)-major) ----------------
__global__ __launch_bounds__(256)
void decode_kernel(const float* __restrict__ f0, const float* __restrict__ f1,
                   const float* __restrict__ f2, const float* __restrict__ anchors,
                   const float* __restrict__ ishape,
                   float* __restrict__ boxes, float* __restrict__ conf2)
{
    int r = blockIdx.x*blockDim.x + threadIdx.x;
    int b = blockIdx.y;
    if (r >= TPAD) return;
    int sa, p;
    if (r < 1092){ sa = r/364; p = r - sa*364; }
    else if (r < 5424){ int q = r-1092; sa = 3 + q/1444; p = q - (sa-3)*1444; }
    else { int q = r-5424; sa = 6 + q/5776; p = q - (sa-6)*5776; }
    int s = (sa>=6)?2:((sa>=3)?1:0);
    int a = sa - 3*s;
    const float* f; int P, G, off, abase;
    if (s==0){ f=f0; P=P0; G=19; off=0;    abase=6; }
    else if (s==1){ f=f1; P=P1; G=38; off=1083; abase=3; }
    else        { f=f2; P=P2; G=76; off=5415; abase=0; }
    size_t cidx = (size_t)b*TPAD + r;
    if (p >= P){ conf2[cidx] = 0.0f; return; }

    const float* fb = f + ((size_t)b*255 + a*85)*(size_t)P;
    float tx = fb[(size_t)0*P + p];
    float ty = fb[(size_t)1*P + p];
    float tw = fb[(size_t)2*P + p];
    float th = fb[(size_t)3*P + p];
    float tc = fb[(size_t)4*P + p];
    int yy = p / G, xx = p - yy*G;
    float g = (float)G;
    float aw = anchors[(abase+a)*2+0];
    float ah = anchors[(abase+a)*2+1];
    float xn = (sigf(tx) + (float)xx) / g;
    float yn = (sigf(ty) + (float)yy) / g;
    float wn = aw * expf(tw) / 608.0f;
    float hn = ah * expf(th) / 608.0f;
    float ih = ishape[0], iw = ishape[1];
    float m  = fminf(608.0f/ih, 608.0f/iw);
    float nh = rintf(ih*m), nw = rintf(iw*m);
    float offy = (608.0f - nh) / 2.0f / 608.0f;
    float offx = (608.0f - nw) / 2.0f / 608.0f;
    float scy = 608.0f/nh, scx = 608.0f/nw;
    float y = (yn - offy)*scy;
    float x = (xn - offx)*scx;
    float hh = hn*scy, ww = wn*scx;
    int n = off + p*3 + a;
    size_t o = ((size_t)b*NBOX + n)*4;
    boxes[o+0] = (y - hh/2.0f)*ih;
    boxes[o+1] = (x - ww/2.0f)*iw;
    boxes[o+2] = (y + hh/2.0f)*ih;
    boxes[o+3] = (x + ww/2.0f)*iw;

    conf2[cidx] = sigf(tc);
}

// ---------------- dense scan over all boxes for a class-pair ----------------
template<int PASS>
__device__ __forceinline__ void scan_pair(const float* __restrict__ f0,
        const float* __restrict__ f1, const float* __restrict__ f2,
        const float* __restrict__ conf2,
        int b, int c0, int tid, int Tb0, int Tb1,
        unsigned int (*hist)[256], float (*cs)[CAP], int (*ci)[CAP], int* cnt)
{
    const float* fs[3] = {f0, f1, f2};
    const int Pact[9] = {361,361,361,1444,1444,1444,5776,5776,5776};
    const int Ppad[9] = {364,364,364,1444,1444,1444,5776,5776,5776};
    const int gsa[9]  = {0,364,728,1092,2536,3980,5424,11200,16976};
    const int offs_s[3] = {0,1083,5415};
#pragma unroll
    for (int sa=0; sa<9; sa++){
        const int s = sa/3, a = sa - 3*(sa/3);
        const int P = Pact[sa];
        const float* prob0 = fs[s] + ((size_t)b*255 + a*85 + 5 + c0)*(size_t)P;
        const float* prob1 = prob0 + P;   // c0+1 is the adjacent channel row
        const float* cf = conf2 + (size_t)b*TPAD + gsa[sa];
        const int nb = offs_s[s] + a;
        const int q4 = Ppad[sa] >> 2;
        for (int i=tid; i<q4; i+=256){
            int p = i<<2;
            float4 c4 = *(const float4*)(cf + p);
            float pa0,pa1,pa2,pa3, pb0,pb1,pb2,pb3;
            if (p + 3 < P){
                float4 t = *(const float4*)(prob0 + p);
                pa0=t.x; pa1=t.y; pa2=t.z; pa3=t.w;
                t = *(const float4*)(prob1 + p);
                pb0=t.x; pb1=t.y; pb2=t.z; pb3=t.w;
            } else {
                pa0 = (p   < P) ? prob0[p]   : -INFINITY;
                pa1 = (p+1 < P) ? prob0[p+1] : -INFINITY;
                pa2 = (p+2 < P) ? prob0[p+2] : -INFINITY;
                pa3 = (p+3 < P) ? prob0[p+3] : -INFINITY;
                pb0 = (p   < P) ? prob1[p]   : -INFINITY;
                pb1 = (p+1 < P) ? prob1[p+1] : -INFINITY;
                pb2 = (p+2 < P) ? prob1[p+2] : -INFINITY;
                pb3 = (p+3 < P) ? prob1[p+3] : -INFINITY;
            }
#define DOJ(CLS, J, PR, CC, TB) { \
            float sc = (CC) * sigf(PR); \
            if (sc > 0.3f){ \
                int bin = (int)(__float_as_uint(sc)>>16) - 0x3E99; \
                bin = bin < 0 ? 0 : (bin > 255 ? 255 : bin); \
                if (PASS == 0) atomicAdd(&hist[CLS][bin], 1u); \
                else if (bin >= (TB)){ \
                    int pos = atomicAdd(&cnt[CLS], 1); \
                    if (pos < CAP){ cs[CLS][pos] = sc; ci[CLS][pos] = nb + 3*(p+J); } } } }
            DOJ(0,0,pa0,c4.x,Tb0) DOJ(0,1,pa1,c4.y,Tb0) DOJ(0,2,pa2,c4.z,Tb0) DOJ(0,3,pa3,c4.w,Tb0)
            DOJ(1,0,pb0,c4.x,Tb1) DOJ(1,1,pb1,c4.y,Tb1) DOJ(1,2,pb2,c4.z,Tb1) DOJ(1,3,pb3,c4.w,Tb1)
#undef DOJ
        }
    }
}

// ------- fused: hist -> Tb -> compact -> adaptive bitonic -> NMS -> out -------
__global__ __launch_bounds__(256)
void select_kernel(const float* __restrict__ f0, const float* __restrict__ f1,
                   const float* __restrict__ f2, const float* __restrict__ conf2,
                   const float* __restrict__ boxes, float* __restrict__ out)
{
    int pair = blockIdx.x, b = blockIdx.y, tid = threadIdx.x;
    int c0 = pair*2;
    __shared__ unsigned int hist[2][256];
    __shared__ int sufA[256], sufB[256];
    __shared__ float cs[2][CAP];
    __shared__ int   ci[2][CAP];
    __shared__ int cnt[2];
    __shared__ int TbS[2];

    hist[0][tid] = 0; hist[1][tid] = 0;
    if (tid < 2){ cnt[tid] = 0; TbS[tid] = 0; }
    __syncthreads();

    // pass 0: per-class histograms
    scan_pair<0>(f0,f1,f2,conf2,b,c0,tid,0,0,hist,cs,ci,cnt);
    __syncthreads();

    // per-class suffix sum -> threshold bin
#pragma unroll
    for (int cls=0; cls<2; cls++){
        sufA[tid] = (int)hist[cls][tid];
        __syncthreads();
        int* cur = sufA; int* nxt = sufB;
        for (int d=1; d<256; d<<=1){
            int v = cur[tid] + ((tid+d) < 256 ? cur[tid+d] : 0);
            nxt[tid] = v;
            __syncthreads();
            int* t_ = cur; cur = nxt; nxt = t_;
        }
        if (cur[tid] >= TOPK && (tid == 255 || cur[tid+1] < TOPK)) TbS[cls] = tid;
        __syncthreads();
    }

    // init candidate buffers
    for (int t=tid; t<CAP; t+=256){
        cs[0][t] = -INFINITY; ci[0][t] = 0x7FFFFFFF;
        cs[1][t] = -INFINITY; ci[1][t] = 0x7FFFFFFF;
    }
    __syncthreads();
    int Tb0 = TbS[0], Tb1 = TbS[1];

    // pass 1: compact candidates
    scan_pair<1>(f0,f1,f2,conf2,b,c0,tid,Tb0,Tb1,hist,cs,ci,cnt);
    __syncthreads();

    // adaptive bitonic per class: score desc, idx asc
#pragma unroll
    for (int cls=0; cls<2; cls++){
        int n = cnt[cls]; if (n > CAP) n = CAP;
        int S = 128; while (S < n) S <<= 1;
        for (int k=2; k<=S; k<<=1){
            for (int j=k>>1; j>0; j>>=1){
                for (int t=tid; t<S; t+=256){
                    int ixj = t ^ j;
                    if (ixj > t){
                        float s1 = cs[cls][t], s2 = cs[cls][ixj];
                        int   i1 = ci[cls][t], i2 = ci[cls][ixj];
                        bool b2_first = (s2 > s1) || (s2 == s1 && i2 < i1);
                        bool b1_first = (s1 > s2) || (s1 == s2 && i1 < i2);
                        bool desc = ((t & k) == 0);
                        bool sw = desc ? b2_first : b1_first;
                        if (sw){ cs[cls][t]=s2; cs[cls][ixj]=s1; ci[cls][t]=i2; ci[cls][ixj]=i1; }
                    }
                }
                __syncthreads();
            }
        }
    }
    __syncthreads();

    // NMS: wave w handles class c0+w (single wave, shfl broadcast, no barriers)
    int w = tid >> 6, lane = tid & 63;
    if (w < 2){
        int c = c0 + w;
        int o0 = (b*NCLS + c)*TOPK;
        float ay1=0.f,ax1=0.f,ay2=0.f,ax2=0.f,aar=0.f,asc=0.f; int ak=0;
        float by1=0.f,bx1=0.f,by2=0.f,bx2=0.f,bar_=0.f,bsc=0.f; int bk=0;
        {
            float s = cs[w][lane];
            if (s > 0.3f){
                asc = s;
                size_t q = ((size_t)b*NBOX + ci[w][lane])*4;
                ay1=boxes[q]; ax1=boxes[q+1]; ay2=boxes[q+2]; ax2=boxes[q+3]; ak=1;
            }
            aar = (ay2-ay1)*(ax2-ax1);
        }
        if (lane + 64 < TOPK){
            float s = cs[w][lane+64];
            if (s > 0.3f){
                bsc = s;
                size_t q = ((size_t)b*NBOX + ci[w][lane+64])*4;
                by1=boxes[q]; bx1=boxes[q+1]; by2=boxes[q+2]; bx2=boxes[q+3]; bk=1;
            }
            bar_ = (by2-by1)*(bx2-bx1);
        }
        for (int i=0; i<TOPK; i++){
            float iy1,ix1,iy2,ix2,iar; int ik;
            if (i < 64){
                iy1=__shfl(ay1,i); ix1=__shfl(ax1,i); iy2=__shfl(ay2,i); ix2=__shfl(ax2,i);
                iar=__shfl(aar,i); ik=__shfl(ak,i);
            } else {
                int l = i - 64;
                iy1=__shfl(by1,l); ix1=__shfl(bx1,l); iy2=__shfl(by2,l); ix2=__shfl(bx2,l);
                iar=__shfl(bar_,l); ik=__shfl(bk,l);
            }
            if (ik){
                if (ak && lane > i){
                    float t1=fmaxf(iy1,ay1), t2=fmaxf(ix1,ax1);
                    float t3=fminf(iy2,ay2), t4=fminf(ix2,ax2);
                    float inter = fmaxf(t3-t1,0.0f)*fmaxf(t4-t2,0.0f);
                    float iou = inter/(iar + aar - inter + 1e-9f);
                    if (iou > 0.3f) ak = 0;
                }
                if (bk && lane + 64 > i){
                    float t1=fmaxf(iy1,by1), t2=fmaxf(ix1,bx1);
                    float t3=fminf(iy2,by2), t4=fminf(ix2,bx2);
                    float inter = fmaxf(t3-t1,0.0f)*fmaxf(t4-t2,0.0f);
                    float iou = inter/(iar + bar_ - inter + 1e-9f);
                    if (iou > 0.3f) bk = 0;
                }
            }
        }
        {
            float k = ak ? 1.0f : 0.0f;
            size_t o5 = ((size_t)(o0+lane))*5;
            out[o5+0]=ay1*k; out[o5+1]=ax1*k; out[o5+2]=ay2*k; out[o5+3]=ax2*k; out[o5+4]=asc*k;
        }
        if (lane + 64 < TOPK){
            float k = bk ? 1.0f : 0.0f;
            size_t o5 = ((size_t)(o0+lane+64))*5;
            out[o5+0]=by1*k; out[o5+1]=bx1*k; out[o5+2]=by2*k; out[o5+3]=bx2*k; out[o5+4]=bsc*k;
        }
    }
}

// ---------------- per-image top-50 cap (1024 threads, shfl reductions) --------
__global__ __launch_bounds__(1024)
void cap_kernel(float* __restrict__ out)
{
    int b = blockIdx.x, tid = threadIdx.x;
    int lane = tid & 63, w = tid >> 6;
    __shared__ float sv[NSLOT];
    __shared__ unsigned char msk[NSLOT];
    __shared__ float wrv[16];
    __shared__ int   wri[16];
    for (int u=tid; u<NSLOT; u+=1024){
        sv[u] = out[((size_t)b*NSLOT + u)*5 + 4];
        msk[u] = 0;
    }
    __syncthreads();
    for (int it=0; it<50; it++){
        float bv = -INFINITY; int bi = 0x7FFFFFFF;
        for (int u=tid; u<NSLOT; u+=1024){
            float v = sv[u];
            if (v > bv){ bv = v; bi = u; }
        }
        for (int off=32; off; off>>=1){
            float v2 = __shfl_xor(bv, off); int i2 = __shfl_xor(bi, off);
            if (v2 > bv || (v2 == bv && i2 < bi)){ bv = v2; bi = i2; }
        }
        if (lane == 0){ wrv[w] = bv; wri[w] = bi; }
        __syncthreads();
        if (w == 0){
            float v = (lane < 16) ? wrv[lane] : -INFINITY;
            int   i = (lane < 16) ? wri[lane] : 0x7FFFFFFF;
            for (int off=8; off; off>>=1){
                float v2 = __shfl_xor(v, off); int i2 = __shfl_xor(i, off);
                if (v2 > v || (v2 == v && i2 < i)){ v = v2; i = i2; }
            }
            if (lane == 0){ msk[i] = 1; sv[i] = -INFINITY; }
        }
        __syncthreads();
    }
    for (int u=tid; u<NSLOT; u+=1024){
        if (!msk[u]){
            size_t o5 = ((size_t)b*NSLOT + u)*5;
            out[o5+0]=0.f; out[o5+1]=0.f; out[o5+2]=0.f; out[o5+3]=0.f; out[o5+4]=0.f;
        }
    }
}

extern "C" void kernel_launch(void* const* d_in, const int* in_sizes, int n_in,
                              void* d_out, int out_size, void* d_ws, size_t ws_size,
                              hipStream_t stream)
{
    const float* f0 = (const float*)d_in[0];
    const float* f1 = (const float*)d_in[1];
    const float* f2 = (const float*)d_in[2];
    const float* anchors = (const float*)d_in[3];
    const float* ishape  = (const float*)d_in[4];
    float* out = (float*)d_out;

    float* boxes = (float*)d_ws;                               // 16*22743*4 floats
    float* conf2 = boxes + (size_t)BATCH*NBOX*4;               // 16*22752

    dim3 dgrid((TPAD + 255)/256, BATCH);
    decode_kernel<<<dgrid, 256, 0, stream>>>(f0, f1, f2, anchors, ishape,
                                             boxes, conf2);

    dim3 sgrid(NCLS/2, BATCH);
    select_kernel<<<sgrid, 256, 0, stream>>>(f0, f1, f2, conf2, boxes, out);

    cap_kernel<<<BATCH, 1024, 0, stream>>>(out);
}